// Round 12
// baseline (51.876 us; speedup 1.0000x reference)
//
#include <hip/hip_runtime.h>
#include <hip/hip_bf16.h>

#define N_DIM   3072
#define BATCH_N 8192
#define K_FIX   30

typedef __attribute__((ext_vector_type(8)))  short short8v;   // 8 bf16
typedef __attribute__((ext_vector_type(16))) float f32x16;

#define CG     32
#define NCG    (N_DIM / CG)          // 96 col groups
#define BCOLS  256                   // out cols per block (8 waves)
#define NCT    (N_DIM / BCOLS)       // 12 col tiles
#define NRG    (BATCH_N / 32)        // 256 row groups
#define PGRAN  80                    // LDS granules (16B) per row (320 cols)
#define NGRAN  (32 * PGRAN)          // 2560 granules per block
#define BTAB_BYTES (NCG * 4 * 64 * sizeof(short8v))   // 393,216 B

static __device__ __forceinline__ short bfs(float f) {
    __hip_bfloat16 h = __float2bfloat16(f);       // RNE; compiler pairs into
    return __builtin_bit_cast(short, h);          // v_cvt_pk_bf16_f32 (m240)
}

static __device__ __forceinline__ short8v pack8(const float4 a, const float4 b) {
    short8v r;
    r[0] = bfs(a.x); r[1] = bfs(a.y); r[2] = bfs(a.z); r[3] = bfs(a.w);
    r[4] = bfs(b.x); r[5] = bfs(b.y); r[6] = bfs(b.z); r[7] = bfs(b.w);
    return r;
}

// ---- B-fragment build (band of W^T) ----
// Bf[step][jj]: k = 16*step + hi*8 + jj, i = j + 32 - k, B = V[i][cg0-32+k].
static __device__ __forceinline__ short8v build_bfrag(
    const float* __restrict__ V, int cg0, int j, int hi, int step)
{
    short8v v8;
    #pragma unroll
    for (int jj = 0; jj < 8; ++jj) {
        const int k = 16 * step + hi * 8 + jj;
        const int i = j + 32 - k;
        short v = 0;
        if (i >= 0 && i < K_FIX) {
            int c = cg0 - 32 + k;
            if (c < 0) c += N_DIM;
            v = bfs(V[(size_t)i * N_DIM + c]);
        }
        v8[jj] = v;
    }
    return v8;
}

// ---------------- pre-kernel: materialize B-fragment table into d_ws --------
__global__ __launch_bounds__(64)
void build_btab(const float* __restrict__ V, const int* __restrict__ dp,
                short8v* __restrict__ btab)
{
    bool ok = true;
    #pragma unroll
    for (int i = 0; i < K_FIX; ++i) ok = ok && (dp[i] == i);
    if (!ok) return;

    const int cgi  = (int)blockIdx.x;
    const int lane = (int)threadIdx.x;
    const int j    = lane & 31;
    const int hi   = lane >> 5;
    const int cg0  = cgi * CG;
    #pragma unroll
    for (int step = 0; step < 4; ++step)
        btab[(cgi * 4 + step) * 64 + lane] = build_bfrag(V, cg0, j, hi, step);
}

// ---------------- Path 1: global_load_lds MFMA band-GEMM --------------------
// R11 post-mortem: VGPR=24 -> register-destined staging loads serialized into
// ~9 memory round-trips per wave (~31k cyc wave lifetime by Little's law).
// Fix: stage via __builtin_amdgcn_global_load_lds width=16 (NO dest VGPRs ->
// issue order can't be serialized by the allocator; one vmcnt drain at the
// barrier).  gload_lds writes wave-uniform base + lane*16 LINEARLY, so the
// LDS stays linear and the R10/R11 XOR swizzle moves to the per-lane GLOBAL
// source address (rule #21 / m173): LDS slot s of row r <- global granule
// s ^ (r&15); the (verified) swizzled ds_read of logical granule g at slot
// g^(j&15) is unchanged.  Rows padded to 80 granules, source wrapped mod N.
// C/D layout (m74/m101): col = lane&31, row = (reg&3)+8*(reg>>2)+4*(lane>>5).
template<bool USE_TAB>
__global__ __launch_bounds__(512)
void fc_diag_mfma32(const float* __restrict__ x, const float* __restrict__ V,
                    const int* __restrict__ dp, const short8v* __restrict__ btab,
                    float* __restrict__ out)
{
    bool ok = true;
    #pragma unroll
    for (int i = 0; i < K_FIX; ++i) ok = ok && (dp[i] == i);
    if (!ok) return;                 // block-uniform: safe w.r.t. barrier

    __shared__ float Xs[NGRAN * 4];          // 40,960 B

    const int tid   = (int)threadIdx.x;
    const int lane  = tid & 63;
    const int wv    = tid >> 6;              // 8 waves
    const int ctile = (int)blockIdx.x % NCT;
    const int rtile = (int)blockIdx.x / NCT;
    const int C0 = ctile * BCOLS;
    const int b0 = rtile * 32;
    const int cgi = ctile * 8 + wv;          // this wave's 32-col group
    const int j    = lane & 31;              // out col within group / A row
    const int hi   = lane >> 5;

    // ---- B fragments: 4 independent 16B loads (issued first) ----
    short8v Bf[4];
    if (USE_TAB) {
        const short8v* bt = btab + (size_t)cgi * 4 * 64 + lane;
        #pragma unroll
        for (int step = 0; step < 4; ++step)
            Bf[step] = bt[(size_t)step * 64];
    } else {
        #pragma unroll
        for (int step = 0; step < 4; ++step)
            Bf[step] = build_bfrag(V, cgi * CG, j, hi, step);
    }

    // ---- stage x tile via global_load_lds (no VGPR round-trip) ----
    // Wave wv covers granule chunks [(wv*5+u)*64, +64).  LDS dest linear:
    // granule G at &Xs[G*4] (HW adds lane*16).  Per-lane source: row = G/80,
    // slot = G%80, global granule = slot ^ (row&15), col wrapped mod N.
    #pragma unroll
    for (int u = 0; u < 5; ++u) {
        const int Gbase = (wv * 5 + u) * 64;
        const int G     = Gbase + lane;
        const int row   = G / PGRAN;
        const int slot  = G - row * PGRAN;
        int c = C0 - 32 + 4 * (slot ^ (row & 15));
        if (c < 0)       c += N_DIM;
        if (c >= N_DIM)  c -= N_DIM;
        const float* gp = x + (size_t)(b0 + row) * N_DIM + c;
        __builtin_amdgcn_global_load_lds(
            (const __attribute__((address_space(1))) unsigned int*)gp,
            (__attribute__((address_space(3))) unsigned int*)&Xs[Gbase * 4],
            16, 0, 0);
    }
    asm volatile("s_waitcnt vmcnt(0)" ::: "memory");
    __syncthreads();

    // ---- A frags from LDS + MFMA (identical to verified R10/R11 path) ----
    // Wave wv needs logical granules wv*8 + hi*2 + 4*step + {0,1} of row j,
    // read at LDS slot g ^ (j&15), row stride 80 granules.
    f32x16 acc = {0.f,0.f,0.f,0.f, 0.f,0.f,0.f,0.f,
                  0.f,0.f,0.f,0.f, 0.f,0.f,0.f,0.f};
    const int gb = wv * 8 + hi * 2;
    #pragma unroll
    for (int step = 0; step < 4; ++step) {
        const int g0 = (gb + 4 * step + 0) ^ (j & 15);
        const int g1 = (gb + 4 * step + 1) ^ (j & 15);
        const float4 h0 = *reinterpret_cast<const float4*>(&Xs[(j * PGRAN + g0) * 4]);
        const float4 h1 = *reinterpret_cast<const float4*>(&Xs[(j * PGRAN + g1) * 4]);
        acc = __builtin_amdgcn_mfma_f32_32x32x16_bf16(pack8(h0, h1), Bf[step],
                                                      acc, 0, 0, 0);
    }

    // ---- store: col = j, row = (reg&3) + 8*(reg>>2) + 4*hi ----
    float* ob = out + (size_t)b0 * N_DIM + C0 + wv * 32 + j;
    #pragma unroll
    for (int reg = 0; reg < 16; ++reg) {
        const int row = (reg & 3) + 8 * (reg >> 2) + 4 * hi;
        ob[(size_t)row * N_DIM] = acc[reg];
    }
}

// ---------------- Path 2: general K=30 (arbitrary diag values) --------------
#define G_NBT   128
#define G_BROWS (BATCH_N / G_NBT)    // 64

__global__ __launch_bounds__(256)
void fc_diag_general30(const float* __restrict__ x, const float* __restrict__ V,
                       const int* __restrict__ dp, float* __restrict__ out)
{
    bool contig = true;
    #pragma unroll
    for (int i = 0; i < K_FIX; ++i) contig = contig && (dp[i] == i);
    if (contig) return;  // fast kernel handled it

    const int NRT2 = N_DIM / 256;
    const int rtile = blockIdx.x % NRT2;
    const int btile = blockIdx.x / NRT2;
    const int r  = rtile * 256 + (int)threadIdx.x;
    const int b0 = btile * G_BROWS;

    int   CI[K_FIX];
    float VW[K_FIX];
    #pragma unroll
    for (int i = 0; i < K_FIX; ++i) {
        int d = dp[i] % N_DIM; if (d < 0) d += N_DIM;
        int c = r - d; if (c < 0) c += N_DIM;
        CI[i] = c;
        VW[i] = V[(size_t)d * N_DIM + c];
    }

    for (int b = b0; b < b0 + G_BROWS; b += 2) {
        const float* xb0 = x + (size_t)b * N_DIM;
        const float* xb1 = xb0 + N_DIM;
        float a0 = 0.f, a1 = 0.f;
        #pragma unroll
        for (int i = 0; i < K_FIX; ++i) {
            const float w = VW[i]; const int c = CI[i];
            a0 = fmaf(xb0[c], w, a0);
            a1 = fmaf(xb1[c], w, a1);
        }
        out[(size_t)b * N_DIM + r]       = a0;
        out[(size_t)(b + 1) * N_DIM + r] = a1;
    }
}

// ---------------- Path 3: naive fallback for K != 30 ------------------------
__global__ void fc_diag_naive(const float* __restrict__ x, const float* __restrict__ V,
                              const int* __restrict__ dp, int K, float* __restrict__ out)
{
    size_t idx   = (size_t)blockIdx.x * blockDim.x + threadIdx.x;
    size_t total = (size_t)BATCH_N * N_DIM;
    size_t step  = (size_t)gridDim.x * blockDim.x;
    for (; idx < total; idx += step) {
        int b = (int)(idx / N_DIM), r = (int)(idx % N_DIM);
        float acc = 0.f;
        for (int i = 0; i < K; ++i) {
            int d = dp[i] % N_DIM; if (d < 0) d += N_DIM;
            int c = r - d; if (c < 0) c += N_DIM;
            acc = fmaf(x[(size_t)b * N_DIM + c], V[(size_t)d * N_DIM + c], acc);
        }
        out[idx] = acc;
    }
}

extern "C" void kernel_launch(void* const* d_in, const int* in_sizes, int n_in,
                              void* d_out, int out_size, void* d_ws, size_t ws_size,
                              hipStream_t stream)
{
    const float* x  = (const float*)d_in[0];
    const float* V  = (const float*)d_in[1];
    const int*   dp = (const int*)d_in[2];
    float* out = (float*)d_out;
    const int K = in_sizes[2];

    if (K == K_FIX) {
        if (ws_size >= BTAB_BYTES) {
            short8v* btab = (short8v*)d_ws;
            build_btab<<<dim3(NCG), dim3(64), 0, stream>>>(V, dp, btab);
            fc_diag_mfma32<true><<<dim3(NCT * NRG), dim3(512), 0, stream>>>(
                x, V, dp, btab, out);
        } else {
            fc_diag_mfma32<false><<<dim3(NCT * NRG), dim3(512), 0, stream>>>(
                x, V, dp, nullptr, out);
        }
        fc_diag_general30<<<dim3((N_DIM / 256) * G_NBT), dim3(256), 0, stream>>>(x, V, dp, out);
    } else {
        fc_diag_naive<<<dim3(2048), dim3(256), 0, stream>>>(x, V, dp, K, out);
    }
}